// Round 4
// baseline (182.570 us; speedup 1.0000x reference)
//
#include <hip/hip_runtime.h>
#include <math.h>

#define LOG2E_F 1.4426950408889634f
#define LN2_F   0.6931471805599453f

constexpr int Bn = 1024;
constexpr int Tn = 512;
constexpr int Ln = 32;

// One 64-lane wave handles TWO batches (two independent recursion chains
// interleaved in the instruction stream for ILP). Within a chain:
//   lanes 0..31 (g=0): forward recursion t in [0, m)
//   lanes 32..63 (g=1): backward recursion t in [m, len)
// Wave-synchronous single-wave block: DS pipe is in-order per wave and the
// write/read dependence is through the same __shared__ array, so no barriers.
// Gold-path score is fused in (computed before the recursion), so this is
// the only kernel.

struct Chain {
    const float* xb;     // batch logits base
    const float* xp;     // emission stream pointer (this lane)
    float* wb;           // this lane's group broadcast buffer (32 floats)
    float* p0;           // group-0 buffer base
    float* p1;           // group-1 buffer base
    float s, M;          // exp-domain state and log2 offset
    float xn0, xn1, xn2, xn3;   // 4-deep emission prefetch
    int Kme, Kw;
    float gold;
};

__global__ __launch_bounds__(64)
void crf_fused_kernel(const float* __restrict__ logits,
                      const float* __restrict__ trans,
                      const int* __restrict__ labels,
                      const int* __restrict__ seq_lens,
                      float* __restrict__ out)
{
    __shared__ __align__(16) float buf[2][2][Ln];   // [chain][group][label]

    const int lane = threadIdx.x;     // 0..63
    const int g    = lane >> 5;       // 0 = fw, 1 = bw
    const int j    = lane & 31;       // label index this lane owns
    const int b0   = blockIdx.x * 2;
    const int b1   = b0 + 1;
    const int dt   = (g == 0) ? Ln : -Ln;

    // ---- gold path scores (independent of recursion; loads issued early) ----
    auto gold_score = [&](int b) -> float {
        int len = seq_lens[b];
        len = len < 1 ? 1 : (len > Tn ? Tn : len);
        const int*   lb = labels + (size_t)b * Tn;
        const float* xb = logits + (size_t)b * (Tn * Ln);
        float acc = 0.f;
        for (int t = lane; t < len; t += 64) {
            const int lt = lb[t];
            acc += xb[t * Ln + lt];
            if (t >= 1) acc += trans[lb[t - 1] * Ln + lt];
        }
        #pragma unroll
        for (int off = 1; off < 64; off <<= 1)
            acc += __shfl_xor(acc, off);
        return acc;
    };
    const float gold0 = gold_score(b0);
    const float gold1 = gold_score(b1);

    // ---- transition fragment (shared by both chains) ----
    // fw lane j holds column j of trans, bw lane j holds row j.
    float E[Ln];
    float tmax = -3.4e38f;
    #pragma unroll
    for (int i = 0; i < Ln; ++i) {
        const float tv = (g == 0) ? trans[i * Ln + j] : trans[j * Ln + i];
        E[i] = tv;
        tmax = fmaxf(tmax, tv);
    }
    #pragma unroll
    for (int off = 1; off < 64; off <<= 1)
        tmax = fmaxf(tmax, __shfl_xor(tmax, off));        // global trans max
    const float tmax2 = tmax * LOG2E_F;                   // per-step M increment
    #pragma unroll
    for (int i = 0; i < Ln; ++i)
        E[i] = __builtin_amdgcn_exp2f((E[i] - tmax) * LOG2E_F);  // E in [e^-1, 1]

    // ---- chain init ----
    Chain c0, c1;
    auto init_chain = [&](Chain& ch, int b, float* q0, float* q1) {
        int len = seq_lens[b];
        len = len < 1 ? 1 : (len > Tn ? Tn : len);
        const int m  = len < (Tn / 2) ? len : (Tn / 2);
        const int Kf = m - 1;
        const int Kb = len - m;
        ch.Kw  = Kf > Kb ? Kf : Kb;
        ch.Kme = (g == 0) ? Kf : Kb;
        ch.xb  = logits + (size_t)b * (Tn * Ln);
        ch.p0 = q0; ch.p1 = q1;
        ch.wb = g ? q1 : q0;

        const float a0 = ch.xb[j] * LOG2E_F;
        float mx = a0;
        #pragma unroll
        for (int off = 1; off < 32; off <<= 1)
            mx = fmaxf(mx, __shfl_xor(mx, off));          // group-local max
        ch.s = (g == 0) ? __builtin_amdgcn_exp2f(a0 - mx) : 1.0f;
        ch.M = (g == 0) ? mx : 0.0f;

        ch.xp = ch.xb + ((g == 0) ? 1 : (len - 1)) * Ln + j;
        { const float* p = ch.xp;          if (p < ch.xb) p = ch.xb; ch.xn0 = *p; }
        { const float* p = ch.xp + dt;     if (p < ch.xb) p = ch.xb; ch.xn1 = *p; }
        { const float* p = ch.xp + 2*dt;   if (p < ch.xb) p = ch.xb; ch.xn2 = *p; }
        { const float* p = ch.xp + 3*dt;   if (p < ch.xb) p = ch.xb; ch.xn3 = *p; }
        ch.xp += 4 * dt;
    };
    init_chain(c0, b0, &buf[0][0][0], &buf[0][1][0]);
    init_chain(c1, b1, &buf[1][0][0], &buf[1][1][0]);

    const int KwMax = c0.Kw > c1.Kw ? c0.Kw : c1.Kw;
    const int KW4   = (KwMax + 3) & ~3;    // inert steps are exact no-ops

    // ---- main recursion: two chains interleaved ----
    auto step = [&](Chain& ch, float& xn, int R, int k) {
        const float xv = xn;
        { const float* p = ch.xp; if (p < ch.xb) p = ch.xb; xn = *p; }  // refill k+4
        ch.xp += dt;

        const float gg = __builtin_amdgcn_exp2f(xv * LOG2E_F);
        const float w  = (g == 0) ? ch.s : ch.s * gg;     // bw applies emission first
        ch.wb[j] = w;

        float q0 = 0.f, q1 = 0.f, q2 = 0.f, q3 = 0.f, cc = 1.0f;
        #pragma unroll
        for (int c = 0; c < 8; ++c) {
            const float4 q = *(const float4*)(ch.wb + 4 * c);   // broadcast read
            if (c == 0) cc = q.x;                                // free renorm const
            q0 = fmaf(q.x, E[4 * c + 0], q0);
            q1 = fmaf(q.y, E[4 * c + 1], q1);
            q2 = fmaf(q.z, E[4 * c + 2], q2);
            q3 = fmaf(q.w, E[4 * c + 3], q3);
        }
        const float dot  = (q0 + q1) + (q2 + q3);
        const float snew = (g == 0) ? dot * gg : dot;

        const bool act = (k <= ch.Kme);
        ch.s = act ? snew : ch.s;
        ch.M = act ? (ch.M + tmax2) : ch.M;

        if (R == 3) {   // renorm by w[0] (uniform across group; ratio bounded)
            ch.s *= __builtin_amdgcn_rcpf(cc);
            ch.M += __builtin_amdgcn_logf(cc);            // v_log_f32 = log2
        }
    };

    for (int k4 = 1; k4 <= KW4; k4 += 4) {
        step(c0, c0.xn0, 0, k4 + 0);  step(c1, c1.xn0, 0, k4 + 0);
        step(c0, c0.xn1, 1, k4 + 1);  step(c1, c1.xn1, 1, k4 + 1);
        step(c0, c0.xn2, 2, k4 + 2);  step(c1, c1.xn2, 2, k4 + 2);
        step(c0, c0.xn3, 3, k4 + 3);  step(c1, c1.xn3, 3, k4 + 3);
    }

    // ---- combine and write: lognorm = Mf + Mb + log2( sum_j sf_j * sb_j ) ----
    auto combine = [&](Chain& ch, int b, float gold) {
        ch.wb[j] = ch.s;
        float term = ch.p0[j] * ch.p1[j];
        #pragma unroll
        for (int off = 1; off < 32; off <<= 1)
            term += __shfl_xor(term, off);
        const float Mo = __shfl_xor(ch.M, 32);
        if (lane == 0)
            out[b] = gold - (ch.M + Mo + __builtin_amdgcn_logf(term)) * LN2_F;
    };
    combine(c0, b0, gold0);
    combine(c1, b1, gold1);
}

extern "C" void kernel_launch(void* const* d_in, const int* in_sizes, int n_in,
                              void* d_out, int out_size, void* d_ws, size_t ws_size,
                              hipStream_t stream) {
    const float* logits   = (const float*)d_in[0];
    const float* trans    = (const float*)d_in[1];
    const int*   labels   = (const int*)d_in[2];
    const int*   seq_lens = (const int*)d_in[3];
    float* out = (float*)d_out;

    crf_fused_kernel<<<Bn / 2, 64, 0, stream>>>(logits, trans, labels, seq_lens, out);
}

// Round 5
// 86.050 us; speedup vs baseline: 2.1217x; 2.1217x over previous
//
#include <hip/hip_runtime.h>
#include <math.h>

#define LOG2E_F 1.4426950408889634f
#define LN2_F   0.6931471805599453f

constexpr int Bn = 1024;
constexpr int Tn = 512;
constexpr int Ln = 32;

// Chain kernel: one 64-lane wave per (batch, direction). 2048 waves total.
// lane l: label j = l&31, half h = l>>5. Each lane keeps the h-half partial
// of state component s_j:  s_j = p(j,0) + p(j,1).
// Per step: all lanes write partials to sbuf[h*32+j]; readers sum both half
// arrays (broadcast ds_read_b128) and dot with their 16-entry E slice.
// Wave-synchronous single-wave block: DS pipe is in-order per wave -> no
// barriers needed (write precedes reads in program order; WAR across steps
// protected by in-order issue).
__global__ __launch_bounds__(64)
void crf_chain_kernel(const float* __restrict__ logits,
                      const float* __restrict__ trans,
                      const int* __restrict__ seq_lens,
                      float* __restrict__ ws)
{
    __shared__ __align__(16) float sbuf[64];

    const int blk  = blockIdx.x;
    const int b    = blk >> 1;
    const int dir  = blk & 1;         // 0 = fw, 1 = bw (uniform per wave)
    const int lane = threadIdx.x;
    const int j    = lane & 31;
    const int h    = lane >> 5;

    int len = seq_lens[b];
    len = len < 1 ? 1 : (len > Tn ? Tn : len);
    const int m  = len < (Tn / 2) ? len : (Tn / 2);
    const int K  = (dir == 0) ? (m - 1) : (len - m);   // uniform per wave
    const int K4 = (K + 3) & ~3;                       // inert steps = no-ops

    const float* xb = logits + (size_t)b * (Tn * Ln);

    // E slice: fw lane (j,h) holds E[i][j], bw holds E[j][i], i in [16h,16h+16)
    float Ei[16];
    float tmax = -3.4e38f;
    #pragma unroll
    for (int e = 0; e < 16; ++e) {
        const int i = 16 * h + e;
        const float tv = (dir == 0) ? trans[i * Ln + j] : trans[j * Ln + i];
        Ei[e] = tv;
        tmax = fmaxf(tmax, tv);
    }
    #pragma unroll
    for (int off = 1; off < 64; off <<= 1)
        tmax = fmaxf(tmax, __shfl_xor(tmax, off));     // global trans max
    const float tmax2 = tmax * LOG2E_F;
    #pragma unroll
    for (int e = 0; e < 16; ++e)
        Ei[e] = __builtin_amdgcn_exp2f((Ei[e] - tmax) * LOG2E_F);  // in [e^-1,1]

    // Init state partial. fw: s_j = 2^(x0_j*log2e - mx); bw: s = 1.
    float p, M;
    if (dir == 0) {
        const float a0 = xb[j] * LOG2E_F;
        float mx = a0;
        #pragma unroll
        for (int off = 1; off < 32; off <<= 1)
            mx = fmaxf(mx, __shfl_xor(mx, off));
        p = (h == 0) ? __builtin_amdgcn_exp2f(a0 - mx) : 0.0f;
        M = mx;
    } else {
        p = (h == 0) ? 1.0f : 0.0f;
        M = 0.0f;
    }

    // Emission stream (this lane's label): fw walks t=1,2,.. bw walks len-1,..
    const int dt = (dir == 0) ? Ln : -Ln;
    const float* xp = xb + ((dir == 0) ? 1 : (len - 1)) * Ln + j;
    float xn0, xn1, xn2, xn3;
    { const float* q = xp;          if (q < xb) q = xb; xn0 = *q; }
    { const float* q = xp + dt;     if (q < xb) q = xb; xn1 = *q; }
    { const float* q = xp + 2*dt;   if (q < xb) q = xb; xn2 = *q; }
    { const float* q = xp + 3*dt;   if (q < xb) q = xb; xn3 = *q; }
    xp += 4 * dt;

    float ggc = __builtin_amdgcn_exp2f(xn0 * LOG2E_F);   // g for step 1

    const int rbase = h << 4;                            // 0 or 16
    const float4* q0p = (const float4*)(sbuf + rbase);        // half-0 partials
    const float4* q1p = (const float4*)(sbuf + 32 + rbase);   // half-1 partials

    for (int k4 = 1; k4 <= K4; k4 += 4) {
        auto step = [&](int R, float& xn, float xnext) {
            const int k  = k4 + R;
            const float gg = ggc;                              // g for step k
            ggc = __builtin_amdgcn_exp2f(xnext * LOG2E_F);     // g for k+1 (off-path)
            { const float* q = xp; if (q < xb) q = xb; xn = *q; }  // refill k+4
            xp += dt;

            // bw applies emission at the writer (distributes over partials)
            sbuf[lane] = (dir == 0) ? p : p * gg;

            float acc0 = 0.f, acc1 = 0.f, acc2 = 0.f, acc3 = 0.f;
            #pragma unroll
            for (int c = 0; c < 4; ++c) {
                const float4 qa = q0p[c];                      // broadcast reads
                const float4 qb = q1p[c];
                acc0 = fmaf(qa.x + qb.x, Ei[4*c+0], acc0);
                acc1 = fmaf(qa.y + qb.y, Ei[4*c+1], acc1);
                acc2 = fmaf(qa.z + qb.z, Ei[4*c+2], acc2);
                acc3 = fmaf(qa.w + qb.w, Ei[4*c+3], acc3);
            }
            const float dotv = (acc0 + acc1) + (acc2 + acc3);
            const float pn   = (dir == 0) ? dotv * gg : dotv;  // fw: reader mul

            const bool act = (k <= K);
            p = act ? pn : p;
            M = act ? (M + tmax2) : M;

            if (R == 3) {   // exact power-of-2 renorm from wave-uniform value
                float cc = sbuf[0] + sbuf[32];                 // s_0 (uniform)
                cc = fmaxf(cc, 1e-30f);
                const int ee = ((__float_as_int(cc) >> 23) & 255) - 127;
                const float sc = __int_as_float((127 - ee) << 23);  // 2^-ee
                p *= sc;
                M += (float)ee;
            }
        };
        step(0, xn0, xn1);
        step(1, xn1, xn2);
        step(2, xn2, xn3);
        step(3, xn3, xn0);   // xn0 already refilled in step(0) -> value for k4+4
    }

    // Final: sum the two half-partials and write state + offset to workspace.
    sbuf[lane] = p;
    const float sfin = p + sbuf[((1 - h) << 5) + j];
    float* wsrow = ws + (size_t)(b * 2 + dir) * 33;
    if (h == 0) {
        wsrow[j] = sfin;
        if (lane == 0) wsrow[32] = M;
    }
}

// Combine kernel: gold path score + lognorm assembly.
__global__ __launch_bounds__(64)
void crf_combine_kernel(const float* __restrict__ logits,
                        const float* __restrict__ trans,
                        const int* __restrict__ labels,
                        const int* __restrict__ seq_lens,
                        const float* __restrict__ ws,
                        float* __restrict__ out)
{
    const int b    = blockIdx.x;
    const int lane = threadIdx.x;
    const int j    = lane & 31;

    int len = seq_lens[b];
    len = len < 1 ? 1 : (len > Tn ? Tn : len);

    const int*   lb = labels + (size_t)b * Tn;
    const float* xb = logits + (size_t)b * (Tn * Ln);

    // gold path score
    float acc = 0.f;
    for (int t = lane; t < len; t += 64) {
        const int lt = lb[t];
        acc += xb[t * Ln + lt];
        if (t >= 1) acc += trans[lb[t - 1] * Ln + lt];
    }
    #pragma unroll
    for (int off = 1; off < 64; off <<= 1)
        acc += __shfl_xor(acc, off);

    // combine fw/bw states
    const float* wf = ws + (size_t)(b * 2 + 0) * 33;
    const float* wb = ws + (size_t)(b * 2 + 1) * 33;
    float term = wf[j] * wb[j];
    #pragma unroll
    for (int off = 1; off < 32; off <<= 1)
        term += __shfl_xor(term, off);
    if (lane == 0) {
        const float Mf = wf[32], Mb = wb[32];
        out[b] = acc - (Mf + Mb + __builtin_amdgcn_logf(term)) * LN2_F;
    }
}

extern "C" void kernel_launch(void* const* d_in, const int* in_sizes, int n_in,
                              void* d_out, int out_size, void* d_ws, size_t ws_size,
                              hipStream_t stream) {
    const float* logits   = (const float*)d_in[0];
    const float* trans    = (const float*)d_in[1];
    const int*   labels   = (const int*)d_in[2];
    const int*   seq_lens = (const int*)d_in[3];
    float* out = (float*)d_out;
    float* ws  = (float*)d_ws;    // 2048 * 33 floats = 270 KB

    crf_chain_kernel<<<Bn * 2, 64, 0, stream>>>(logits, trans, seq_lens, ws);
    crf_combine_kernel<<<Bn, 64, 0, stream>>>(logits, trans, labels, seq_lens, ws, out);
}

// Round 6
// 72.686 us; speedup vs baseline: 2.5118x; 1.1839x over previous
//
#include <hip/hip_runtime.h>
#include <math.h>

#define LOG2E_F 1.4426950408889634f
#define LN2_F   0.6931471805599453f

constexpr int Bn = 1024;
constexpr int Tn = 512;
constexpr int Ln = 32;

// Chain kernel: one 64-lane wave per (batch, direction); NO LDS in the loop.
// Logical state x[0..31] (exp-domain, scaled). Layout: lane l holds
// x[pi(l)], pi(l) = (l&31) ^ (l>=32 ? 16 : 0)  ("half-swapped duplicated"),
// so each 16-lane row holds one full contiguous half of x:
//   row0: x[0..15], row1: x[16..31], row2: x[16..31], row3: x[0..15].
// Per step, lane l computes the 16-term partial of y[phi], phi = l&31, over
// the half its row holds, using DPP row-rotates of the live register.
// Pairs (l, l+32) hold complementary halves of the same y -> combine with
// one shfl_xor(32); layout restored with one shfl_xor(16).
__global__ __launch_bounds__(64)
void crf_chain_kernel(const float* __restrict__ logits,
                      const float* __restrict__ trans,
                      const int* __restrict__ seq_lens,
                      float* __restrict__ ws)
{
    const int blk = blockIdx.x;
    const int b   = blk >> 1;
    const int dir = blk & 1;          // 0 = fw, 1 = bw (uniform per wave)
    const int l   = threadIdx.x;
    const int k15 = l & 15;
    const int phi = l & 31;                      // output label this lane owns
    const int ih  = ((l >> 4) ^ (l >> 5)) & 1;   // which half this row holds
    const int pi  = phi ^ ((l >> 5) << 4);       // label of the value this lane holds

    int len = seq_lens[b];
    len = len < 1 ? 1 : (len > Tn ? Tn : len);
    const int m  = len < (Tn / 2) ? len : (Tn / 2);
    const int K  = dir ? (len - m) : (m - 1);    // uniform per wave
    const int K4 = (K + 3) & ~3;                 // inert steps are exact no-ops

    const float* xb = logits + (size_t)b * (Tn * Ln);

    // --- detect DPP row_ror source direction (hardware-truth, not docs) ---
    // ror:1 at lane0 returns lane15's value (src = i-1) or lane1's (src = i+1).
    const int w0 = __builtin_amdgcn_readfirstlane(
        __builtin_amdgcn_update_dpp(0, l, 0x121, 0xF, 0xF, true));
    const bool ror_minus = (w0 == 15);

    // --- E table: Ei[t] pairs with the value arriving under row_ror:t ---
    // value at rot t = x[16*ih + sigma(t)], sigma = (k15 -+ t) & 15.
    float Ei[16];
    float tmax = -3.4e38f;
    #pragma unroll
    for (int t = 0; t < 16; ++t) {
        const int s = ror_minus ? ((k15 - t) & 15) : ((k15 + t) & 15);
        const int i = 16 * ih + s;
        const float tv = dir ? trans[phi * Ln + i] : trans[i * Ln + phi];
        Ei[t] = tv;
        tmax = fmaxf(tmax, tv);
    }
    #pragma unroll
    for (int off = 1; off < 64; off <<= 1)
        tmax = fmaxf(tmax, __shfl_xor(tmax, off));   // global trans max
    const float tmax2 = tmax * LOG2E_F;
    #pragma unroll
    for (int t = 0; t < 16; ++t)
        Ei[t] = __builtin_amdgcn_exp2f((Ei[t] - tmax) * LOG2E_F);  // (0,1]

    // --- init state (in pi-layout) ---
    float x, M;
    if (dir == 0) {
        const float a0 = xb[pi] * LOG2E_F;
        float mx = a0;
        #pragma unroll
        for (int off = 1; off < 64; off <<= 1)
            mx = fmaxf(mx, __shfl_xor(mx, off));
        x = __builtin_amdgcn_exp2f(a0 - mx);
        M = mx;
    } else {
        x = 1.0f;
        M = 0.0f;
    }

    // --- emission stream: fw reads label phi; bw reads label pi (writer-side) ---
    const int loadlab = dir ? pi : phi;
    const int dt = dir ? -Ln : Ln;
    const float* xp = xb + (dir ? (len - 1) : 1) * Ln + loadlab;
    float xn0, xn1, xn2, xn3;
    { const float* q = xp;          if (q < xb) q = xb; xn0 = *q; }
    { const float* q = xp + dt;     if (q < xb) q = xb; xn1 = *q; }
    { const float* q = xp + 2*dt;   if (q < xb) q = xb; xn2 = *q; }
    { const float* q = xp + 3*dt;   if (q < xb) q = xb; xn3 = *q; }
    xp += 4 * dt;

    float ggc = __builtin_amdgcn_exp2f(xn0 * LOG2E_F);   // g for step 1

#define ROTFMA(T) {                                                         \
    const float r_ = __int_as_float(__builtin_amdgcn_update_dpp(            \
        0, __float_as_int(xs), 0x120 + (T), 0xF, 0xF, true));               \
    acc[(T) & 3] = fmaf(r_, Ei[T], acc[(T) & 3]); }

#define STEP(R, XN, XNEXT) {                                                \
    const int k = k4 + (R);                                                 \
    const float gcur = ggc;                                                 \
    ggc = __builtin_amdgcn_exp2f((XNEXT) * LOG2E_F);                        \
    { const float* q = xp; if (q < xb) q = xb; XN = *q; }                   \
    xp += dt;                                                               \
    const float xs = dir ? x * gcur : x;   /* bw: emission at writer */     \
    float acc[4];                                                           \
    acc[0] = xs * Ei[0];                                                    \
    acc[1] = 0.f; acc[2] = 0.f; acc[3] = 0.f;                               \
    ROTFMA(1)  ROTFMA(2)  ROTFMA(3)  ROTFMA(4)  ROTFMA(5)                   \
    ROTFMA(6)  ROTFMA(7)  ROTFMA(8)  ROTFMA(9)  ROTFMA(10)                  \
    ROTFMA(11) ROTFMA(12) ROTFMA(13) ROTFMA(14) ROTFMA(15)                  \
    const float partial = (acc[0] + acc[1]) + (acc[2] + acc[3]);            \
    float full = partial + __shfl_xor(partial, 32);                         \
    if (dir == 0) full *= gcur;            /* fw: emission at reader */     \
    const float fx = __shfl_xor(full, 16);                                  \
    const float cand = (l < 32) ? full : fx;   /* restore pi-layout */      \
    const bool act = (k <= K);                                              \
    x = act ? cand : x;                                                     \
    M = act ? (M + tmax2) : M;                                              \
    if ((R) == 3) {   /* exact pow2 renorm from wave-uniform lane0 value */ \
        const float ccv = fmaxf(x, 1e-30f);                                 \
        const int cb = __builtin_amdgcn_readfirstlane(__float_as_int(ccv)); \
        const int ee = ((cb >> 23) & 255) - 127;                            \
        x *= __int_as_float((127 - ee) << 23);                              \
        M += (float)ee;                                                     \
    } }

    for (int k4 = 1; k4 <= K4; k4 += 4) {
        STEP(0, xn0, xn1)
        STEP(1, xn1, xn2)
        STEP(2, xn2, xn3)
        STEP(3, xn3, xn0)   // xn0 was refilled in STEP(0): emission for k4+4
    }
#undef STEP
#undef ROTFMA

    // Final: lanes 0..31 hold x[phi] (pi==phi there). Write state + offset.
    float* wsrow = ws + (size_t)(b * 2 + dir) * 33;
    if (l < 32) wsrow[l] = x;
    if (l == 0) wsrow[32] = M;
}

// Combine kernel: gold path score + lognorm assembly.
__global__ __launch_bounds__(64)
void crf_combine_kernel(const float* __restrict__ logits,
                        const float* __restrict__ trans,
                        const int* __restrict__ labels,
                        const int* __restrict__ seq_lens,
                        const float* __restrict__ ws,
                        float* __restrict__ out)
{
    const int b    = blockIdx.x;
    const int lane = threadIdx.x;
    const int j    = lane & 31;

    int len = seq_lens[b];
    len = len < 1 ? 1 : (len > Tn ? Tn : len);

    const int*   lb = labels + (size_t)b * Tn;
    const float* xb = logits + (size_t)b * (Tn * Ln);

    // gold path score
    float acc = 0.f;
    for (int t = lane; t < len; t += 64) {
        const int lt = lb[t];
        acc += xb[t * Ln + lt];
        if (t >= 1) acc += trans[lb[t - 1] * Ln + lt];
    }
    #pragma unroll
    for (int off = 1; off < 64; off <<= 1)
        acc += __shfl_xor(acc, off);

    // combine fw/bw states
    const float* wf = ws + (size_t)(b * 2 + 0) * 33;
    const float* wb = ws + (size_t)(b * 2 + 1) * 33;
    float term = wf[j] * wb[j];
    #pragma unroll
    for (int off = 1; off < 32; off <<= 1)
        term += __shfl_xor(term, off);
    if (lane == 0) {
        const float Mf = wf[32], Mb = wb[32];
        out[b] = acc - (Mf + Mb + __builtin_amdgcn_logf(term)) * LN2_F;
    }
}

extern "C" void kernel_launch(void* const* d_in, const int* in_sizes, int n_in,
                              void* d_out, int out_size, void* d_ws, size_t ws_size,
                              hipStream_t stream) {
    const float* logits   = (const float*)d_in[0];
    const float* trans    = (const float*)d_in[1];
    const int*   labels   = (const int*)d_in[2];
    const int*   seq_lens = (const int*)d_in[3];
    float* out = (float*)d_out;
    float* ws  = (float*)d_ws;    // 2048 * 33 floats = 270 KB

    crf_chain_kernel<<<Bn * 2, 64, 0, stream>>>(logits, trans, seq_lens, ws);
    crf_combine_kernel<<<Bn, 64, 0, stream>>>(logits, trans, labels, seq_lens, ws, out);
}

// Round 7
// 68.771 us; speedup vs baseline: 2.6547x; 1.0569x over previous
//
#include <hip/hip_runtime.h>
#include <math.h>

#define LOG2E_F 1.4426950408889634f
#define LN2_F   0.6931471805599453f

constexpr int Bn = 1024;
constexpr int Tn = 512;
constexpr int Ln = 32;

typedef unsigned int uint2v __attribute__((ext_vector_type(2)));

// Chain kernel: one 64-lane wave per (batch, direction); no LDS, no DS-pipe
// ops in the loop (permlane VALU swaps instead of shfl/ds_bpermute).
// Logical state x[0..31] (exp-domain, scaled). Layout: lane l holds
// x[pi(l)], pi(l) = (l&31) ^ (l>=32 ? 16 : 0)  ("half-swapped duplicated"):
//   row0: x[0..15], row1: x[16..31], row2: x[16..31], row3: x[0..15].
// Per step, lane l computes the 16-term partial of y[phi], phi = l&31, over
// the half its row holds via DPP row-rotates; pairs (l, l^32) hold
// complementary halves -> combine via permlane32_swap; layout restored via
// permlane16_swap (upper half takes the xor-16 value).
__global__ __launch_bounds__(64)
void crf_chain_kernel(const float* __restrict__ logits,
                      const float* __restrict__ trans,
                      const int* __restrict__ seq_lens,
                      float* __restrict__ ws)
{
    const int blk = blockIdx.x;
    const int b   = blk >> 1;
    const int dir = blk & 1;          // 0 = fw, 1 = bw (uniform per wave)
    const int l   = threadIdx.x;
    const int k15 = l & 15;
    const int phi = l & 31;                      // output label this lane owns
    const int ih  = ((l >> 4) ^ (l >> 5)) & 1;   // which half this row holds
    const int pi  = phi ^ ((l >> 5) << 4);       // label of the held value

    int len = seq_lens[b];
    len = len < 1 ? 1 : (len > Tn ? Tn : len);
    const int m  = len < (Tn / 2) ? len : (Tn / 2);
    const int K  = dir ? (len - m) : (m - 1);    // uniform per wave
    const int nfull = K >> 2;                    // full groups of 4 steps
    const int ktail = K & 3;

    const float* xb = logits + (size_t)b * (Tn * Ln);

    // --- probe DPP row_ror source direction (hardware truth) ---
    const int w0 = __builtin_amdgcn_readfirstlane(
        __builtin_amdgcn_update_dpp(0, l, 0x121, 0xF, 0xF, true));
    const bool ror_minus = (w0 == 15);

    // --- probe permlane swap output mapping (hardware truth) ---
#if __has_builtin(__builtin_amdgcn_permlane32_swap)
    bool use_y32;
    {
        const uint2v r = __builtin_amdgcn_permlane32_swap((unsigned)l, (unsigned)l, false, false);
        const bool selA = __all((((l < 32) ? (int)r[1] : (int)r[0]) == (l ^ 32)) ? 1 : 0);
        use_y32 = selA ? (l < 32) : (l >= 32);
    }
#define CROSS32(p, out) {                                                    \
    const uint2v r_ = __builtin_amdgcn_permlane32_swap(                      \
        __float_as_uint(p), __float_as_uint(p), false, false);               \
    out = __uint_as_float(use_y32 ? r_[1] : r_[0]); }
#else
#define CROSS32(p, out) out = __shfl_xor((p), 32);
#endif

#if __has_builtin(__builtin_amdgcn_permlane16_swap)
    bool use_r016;
    {
        const uint2v r = __builtin_amdgcn_permlane16_swap((unsigned)l, (unsigned)l, false, false);
        const bool selA = __all(((((l & 16) ? (int)r[0] : (int)r[1])) == (l ^ 16)) ? 1 : 0);
        use_r016 = selA ? ((l & 16) != 0) : ((l & 16) == 0);
    }
#define CROSS16(p, out) {                                                    \
    const uint2v r_ = __builtin_amdgcn_permlane16_swap(                      \
        __float_as_uint(p), __float_as_uint(p), false, false);               \
    out = __uint_as_float(use_r016 ? r_[0] : r_[1]); }
#else
#define CROSS16(p, out) out = __int_as_float(__builtin_amdgcn_ds_swizzle(    \
        __float_as_int(p), 0x401F));   /* BitMode xor=16, and=0x1F */
#endif

    // --- E table: Ei[t] pairs with the value arriving under row_ror:t ---
    float Ei[16];
    float tmax = -3.4e38f;
    #pragma unroll
    for (int t = 0; t < 16; ++t) {
        const int s = ror_minus ? ((k15 - t) & 15) : ((k15 + t) & 15);
        const int i = 16 * ih + s;
        const float tv = dir ? trans[phi * Ln + i] : trans[i * Ln + phi];
        Ei[t] = tv;
        tmax = fmaxf(tmax, tv);
    }
    #pragma unroll
    for (int off = 1; off < 64; off <<= 1)
        tmax = fmaxf(tmax, __shfl_xor(tmax, off));   // global trans max
    const float tmax2 = tmax * LOG2E_F;
    #pragma unroll
    for (int t = 0; t < 16; ++t)
        Ei[t] = __builtin_amdgcn_exp2f((Ei[t] - tmax) * LOG2E_F);  // (0,1]

    // --- init state (pi-layout) ---
    float x, Minit;
    if (dir == 0) {
        const float a0 = xb[pi] * LOG2E_F;
        float mx = a0;
        #pragma unroll
        for (int off = 1; off < 64; off <<= 1)
            mx = fmaxf(mx, __shfl_xor(mx, off));
        x = __builtin_amdgcn_exp2f(a0 - mx);
        Minit = mx;
    } else {
        x = 1.0f;
        Minit = 0.0f;
    }
    float Mr = 0.0f;    // renorm exponent accumulator

    // --- emission stream: fw reads label phi; bw reads label pi ---
    const int loadlab = dir ? pi : phi;
    const int dt = dir ? -Ln : Ln;
    const float* xp = xb + (dir ? (len - 1) : 1) * Ln + loadlab;
    float xn0, xn1, xn2, xn3;
    { const float* q = xp;          if (q < xb) q = xb; xn0 = *q; }
    { const float* q = xp + dt;     if (q < xb) q = xb; xn1 = *q; }
    { const float* q = xp + 2*dt;   if (q < xb) q = xb; xn2 = *q; }
    { const float* q = xp + 3*dt;   if (q < xb) q = xb; xn3 = *q; }
    xp += 4 * dt;

    float ggc = __builtin_amdgcn_exp2f(xn0 * LOG2E_F);   // g for step 1

#define ROTFMA(T) {                                                         \
    const float r_ = __int_as_float(__builtin_amdgcn_update_dpp(            \
        0, __float_as_int(xs), 0x120 + (T), 0xF, 0xF, true));               \
    acc[(T) & 3] = fmaf(r_, Ei[T], acc[(T) & 3]); }

#define STEP_BODY(XN, XNEXT)                                                \
    const float gcur = ggc;                                                 \
    ggc = __builtin_amdgcn_exp2f((XNEXT) * LOG2E_F);                        \
    { const float* q = xp; if (q < xb) q = xb; XN = *q; }                   \
    xp += dt;                                                               \
    const float xs = dir ? x * gcur : x;   /* bw: emission at writer */     \
    float acc[4];                                                           \
    acc[0] = xs * Ei[0];                                                    \
    acc[1] = 0.f; acc[2] = 0.f; acc[3] = 0.f;                               \
    ROTFMA(1)  ROTFMA(2)  ROTFMA(3)  ROTFMA(4)  ROTFMA(5)                   \
    ROTFMA(6)  ROTFMA(7)  ROTFMA(8)  ROTFMA(9)  ROTFMA(10)                  \
    ROTFMA(11) ROTFMA(12) ROTFMA(13) ROTFMA(14) ROTFMA(15)                  \
    const float partial = (acc[0] + acc[1]) + (acc[2] + acc[3]);            \
    float cross; CROSS32(partial, cross)                                    \
    float full = partial + cross;                                           \
    if (dir == 0) full *= gcur;            /* fw: emission at reader */     \
    float fx; CROSS16(full, fx)                                             \
    const float cand = (l < 32) ? full : fx;   /* restore pi-layout */

#define RENORM {                                                            \
    const float ccv = fmaxf(x, 1e-30f);                                     \
    const int cb = __builtin_amdgcn_readfirstlane(__float_as_int(ccv));     \
    const int ee = ((cb >> 23) & 255) - 127;                                \
    x *= __int_as_float((127 - ee) << 23);                                  \
    Mr += (float)ee; }

#define STEPF(R, XN, XNEXT) {                                               \
    STEP_BODY(XN, XNEXT)                                                    \
    x = cand;                                                               \
    if ((R) == 3) RENORM }

#define STEPT(R, XN, XNEXT) {                                               \
    STEP_BODY(XN, XNEXT)                                                    \
    const bool act = ((R) < ktail);                                         \
    x = act ? cand : x;                                                     \
    if ((R) == 3) RENORM }

    for (int gi = 0; gi < nfull; ++gi) {
        STEPF(0, xn0, xn1)
        STEPF(1, xn1, xn2)
        STEPF(2, xn2, xn3)
        STEPF(3, xn3, xn0)   // xn0 refilled in STEPF(0): emission for k+4
    }
    if (ktail) {
        STEPT(0, xn0, xn1)
        STEPT(1, xn1, xn2)
        STEPT(2, xn2, xn3)
        STEPT(3, xn3, xn0)
    }
#undef STEPF
#undef STEPT
#undef STEP_BODY
#undef RENORM
#undef ROTFMA
#undef CROSS32
#undef CROSS16

    const float M = Minit + (float)K * tmax2 + Mr;

    // Final: lanes 0..31 hold x[phi] (pi==phi there). Write state + offset.
    float* wsrow = ws + (size_t)(b * 2 + dir) * 33;
    if (l < 32) wsrow[l] = x;
    if (l == 0) wsrow[32] = M;
}

// Combine kernel: gold path score + lognorm assembly.
__global__ __launch_bounds__(64)
void crf_combine_kernel(const float* __restrict__ logits,
                        const float* __restrict__ trans,
                        const int* __restrict__ labels,
                        const int* __restrict__ seq_lens,
                        const float* __restrict__ ws,
                        float* __restrict__ out)
{
    const int b    = blockIdx.x;
    const int lane = threadIdx.x;
    const int j    = lane & 31;

    int len = seq_lens[b];
    len = len < 1 ? 1 : (len > Tn ? Tn : len);

    const int*   lb = labels + (size_t)b * Tn;
    const float* xb = logits + (size_t)b * (Tn * Ln);

    // gold path score
    float acc = 0.f;
    for (int t = lane; t < len; t += 64) {
        const int lt = lb[t];
        acc += xb[t * Ln + lt];
        if (t >= 1) acc += trans[lb[t - 1] * Ln + lt];
    }
    #pragma unroll
    for (int off = 1; off < 64; off <<= 1)
        acc += __shfl_xor(acc, off);

    // combine fw/bw states
    const float* wf = ws + (size_t)(b * 2 + 0) * 33;
    const float* wb = ws + (size_t)(b * 2 + 1) * 33;
    float term = wf[j] * wb[j];
    #pragma unroll
    for (int off = 1; off < 32; off <<= 1)
        term += __shfl_xor(term, off);
    if (lane == 0) {
        const float Mf = wf[32], Mb = wb[32];
        out[b] = acc - (Mf + Mb + __builtin_amdgcn_logf(term)) * LN2_F;
    }
}

extern "C" void kernel_launch(void* const* d_in, const int* in_sizes, int n_in,
                              void* d_out, int out_size, void* d_ws, size_t ws_size,
                              hipStream_t stream) {
    const float* logits   = (const float*)d_in[0];
    const float* trans    = (const float*)d_in[1];
    const int*   labels   = (const int*)d_in[2];
    const int*   seq_lens = (const int*)d_in[3];
    float* out = (float*)d_out;
    float* ws  = (float*)d_ws;    // 2048 * 33 floats = 270 KB

    crf_chain_kernel<<<Bn * 2, 64, 0, stream>>>(logits, trans, seq_lens, ws);
    crf_combine_kernel<<<Bn, 64, 0, stream>>>(logits, trans, labels, seq_lens, ws, out);
}